// Round 3
// baseline (224.538 us; speedup 1.0000x reference)
//
#include <hip/hip_runtime.h>
#include <math.h>

// Problem constants (match reference)
constexpr int B = 64, J = 8, K = 64, M = 32, D = 256;
constexpr int NNEG = K * M;            // 2048 negatives per batch
constexpr float TEMP = 0.1f;
constexpr float EPS = 1e-8f;
constexpr float SHIFT = 10.0f;         // 1/TEMP upper bound on |sim|

constexpr int SLICES = 8;                       // blocks per batch
constexpr int NEG_PER_BLOCK = NNEG / SLICES;    // 256 negs / block
constexpr int NBLK = B * SLICES;                // 512 blocks
constexpr int TOTAL_WAVES = NBLK * 4;           // 2048 waves

// Workspace layout (zeroed by hipMemsetAsync before launch):
//   ws[0..63]  : per-batch acc  = sum over matching negs of exp(sim-SHIFT)
//                               + exp(pos_sim-SHIFT)
//   ws[64]     : sum of pos_sim over batches
//   ws[65]     : wave-completion counter (as int bits)
__global__ __launch_bounds__(256) void ntxent_fused_kernel(
    const float* __restrict__ childrens,
    const float* __restrict__ childrens_pos,
    const int*   __restrict__ gt_labels,
    const float* __restrict__ negs,
    const int*   __restrict__ neg_labels,
    float*       __restrict__ ws,
    float*       __restrict__ out) {
  const int blk  = blockIdx.x;
  const int b    = blk >> 3;       // / SLICES
  const int s    = blk & 7;        // % SLICES
  const int tid  = threadIdx.x;    // 0..255
  const int lane = tid & 63;
  const int wave = tid >> 6;       // 0..3

  float* acc_buf  = ws;            // [B]
  float* possum_p = ws + B;        // scalar
  unsigned int* counter_p = (unsigned int*)(ws + B + 1);

  // ---- issue all independent loads up front ----
  const float* child = childrens + ((size_t)b * J + (J - 1)) * D;
  const float4 cv = ((const float4*)child)[lane];   // lane i: elems 4i..4i+3
  const int label = gt_labels[b * J + (J - 1)];
  const int neg_base = s * NEG_PER_BLOCK + wave * 64;
  const int nlab = neg_labels[(size_t)b * NNEG + neg_base + lane];

  float4 pv = make_float4(0.f, 0.f, 0.f, 0.f);
  const bool do_pos = (s == 0) && (wave == 0);
  if (do_pos)
    pv = ((const float4*)(childrens_pos + ((size_t)b * J + (J - 1)) * D))[lane];

  // ---- child norm^2, per-wave shuffle reduce (lane 0 holds result) ----
  float ss = cv.x * cv.x + cv.y * cv.y + cv.z * cv.z + cv.w * cv.w;
  #pragma unroll
  for (int off = 32; off > 0; off >>= 1) ss += __shfl_down(ss, off, 64);
  // only lane 0's value is used below

  const float* nv_base = negs + (size_t)b * NNEG * D;
  unsigned long long mask = __ballot(nlab == label);

  float acc = 0.0f;
  const float cn_inv_t = 1.0f / (fmaxf(sqrtf(ss), EPS) * TEMP);  // lane0-valid
  while (mask) {
    // peel up to 4 set bits (wave-uniform); duplicates are cache-hit reloads
    int idx[4];
    int cnt = 1;
    idx[0] = __ffsll((long long)mask) - 1;
    mask &= mask - 1;
    #pragma unroll
    for (int t = 1; t < 4; ++t) {
      if (mask) {
        idx[t] = __ffsll((long long)mask) - 1;
        mask &= mask - 1;
        ++cnt;
      } else {
        idx[t] = idx[0];
      }
    }

    float dot[4], nn[4];
    #pragma unroll
    for (int t = 0; t < 4; ++t) {
      const float4 x =
          ((const float4*)(nv_base + (size_t)(neg_base + idx[t]) * D))[lane];
      dot[t] = cv.x * x.x + cv.y * x.y + cv.z * x.z + cv.w * x.w;
      nn[t]  = x.x * x.x + x.y * x.y + x.z * x.z + x.w * x.w;
    }
    #pragma unroll
    for (int off = 32; off > 0; off >>= 1) {
      #pragma unroll
      for (int t = 0; t < 4; ++t) {
        dot[t] += __shfl_down(dot[t], off, 64);
        nn[t]  += __shfl_down(nn[t],  off, 64);
      }
    }
    if (lane == 0) {
      #pragma unroll
      for (int t = 0; t < 4; ++t) {
        if (t < cnt) {
          const float sim = dot[t] * cn_inv_t / fmaxf(sqrtf(nn[t]), EPS);
          acc += expf(sim - SHIFT);
        }
      }
    }
  }

  // ---- pos_sim (one wave per batch) ----
  if (do_pos) {
    float pp = pv.x * pv.x + pv.y * pv.y + pv.z * pv.z + pv.w * pv.w;
    float cp = cv.x * pv.x + cv.y * pv.y + cv.z * pv.z + cv.w * pv.w;
    #pragma unroll
    for (int off = 32; off > 0; off >>= 1) {
      pp += __shfl_down(pp, off, 64);
      cp += __shfl_down(cp, off, 64);
    }
    if (lane == 0) {
      const float pos_sim = cp * cn_inv_t / fmaxf(sqrtf(pp), EPS);
      acc += expf(pos_sim - SHIFT);
      atomicAdd(possum_p, pos_sim);
    }
  }

  // ---- publish partial, elect last wave ----
  unsigned int old = 0;
  if (lane == 0) {
    if (acc != 0.0f) atomicAdd(acc_buf + b, acc);
    __threadfence();                 // order acc adds before counter add
    old = atomicAdd(counter_p, 1u);
  }
  old = (unsigned int)__shfl((int)old, 0, 64);

  if (old == TOTAL_WAVES - 1) {
    // last wave: all other waves' atomics complete & visible
    __threadfence();
    const float a = atomicAdd(acc_buf + lane, 0.0f);   // coherent read, lane b
    float l = logf(a);
    #pragma unroll
    for (int off = 32; off > 0; off >>= 1) l += __shfl_down(l, off, 64);
    if (lane == 0) {
      const float psum = atomicAdd(possum_p, 0.0f);
      out[0] = (l + (float)B * SHIFT - psum) / (2.0f * B);
    }
  }
}

extern "C" void kernel_launch(void* const* d_in, const int* in_sizes, int n_in,
                              void* d_out, int out_size, void* d_ws, size_t ws_size,
                              hipStream_t stream) {
  const float* childrens      = (const float*)d_in[0];   // (B,J,D)
  const float* childrens_pos  = (const float*)d_in[1];   // (B,J,D)
  const float* childrens_negs = (const float*)d_in[2];   // (B,K,M,D)
  const int*   gt_labels      = (const int*)d_in[3];     // (B,J)
  const int*   gt_label_negs  = (const int*)d_in[4];     // (B,K,M)
  float* out = (float*)d_out;
  float* ws  = (float*)d_ws;

  // zero acc[B] + possum + counter (66 floats)
  hipMemsetAsync(d_ws, 0, (B + 2) * sizeof(float), stream);

  ntxent_fused_kernel<<<NBLK, 256, 0, stream>>>(
      childrens, childrens_pos, gt_labels, childrens_negs, gt_label_negs,
      ws, out);
}

// Round 4
// 176.596 us; speedup vs baseline: 1.2715x; 1.2715x over previous
//
#include <hip/hip_runtime.h>
#include <math.h>

// Problem constants (match reference)
constexpr int B = 64, J = 8, K = 64, M = 32, D = 256;
constexpr int NNEG = K * M;            // 2048 negatives per batch
constexpr float TEMP = 0.1f;
constexpr float EPS = 1e-8f;
constexpr float SHIFT = 10.0f;         // 1/TEMP upper bound on |sim|

constexpr int SLICES = 8;                       // blocks per batch
constexpr int NEG_PER_BLOCK = NNEG / SLICES;    // 256 negs / block
constexpr int NBLK = B * SLICES;                // 512 blocks

// Kernel 1: per-(batch, slice) partial sum of exp(neg_sim - SHIFT) over
// label-matching negatives. Labels checked BEFORE reading the 1 KB vectors
// -> only ~1/16 of the 128 MB negs array is fetched. Zero LDS, zero
// barriers: each wave is fully independent. Match loop peels up to 8 set
// bits per round (8 independent float4 loads in flight) to cut the
// binomial-tail serialization. Slice-0/wave-0 computes pos_sim and folds
// exp(pos_sim-SHIFT) into its partial.
__global__ __launch_bounds__(256) void neg_partial_kernel(
    const float* __restrict__ childrens,
    const float* __restrict__ childrens_pos,
    const int*   __restrict__ gt_labels,
    const float* __restrict__ negs,
    const int*   __restrict__ neg_labels,
    float*       __restrict__ partials,
    float*       __restrict__ pos_sims) {
  const int blk  = blockIdx.x;
  const int b    = blk >> 3;       // / SLICES
  const int s    = blk & 7;        // % SLICES
  const int tid  = threadIdx.x;    // 0..255
  const int lane = tid & 63;
  const int wave = tid >> 6;       // 0..3

  // ---- issue all independent loads up front ----
  const float* child = childrens + ((size_t)b * J + (J - 1)) * D;
  const float4 cv = ((const float4*)child)[lane];   // lane i: elems 4i..4i+3
  const int label = gt_labels[b * J + (J - 1)];
  const int neg_base = s * NEG_PER_BLOCK + wave * 64;
  const int nlab = neg_labels[(size_t)b * NNEG + neg_base + lane];

  float4 pv = make_float4(0.f, 0.f, 0.f, 0.f);
  const bool do_pos = (s == 0) && (wave == 0);
  if (do_pos)
    pv = ((const float4*)(childrens_pos + ((size_t)b * J + (J - 1)) * D))[lane];

  // ---- child norm^2, per-wave shuffle reduce (lane 0 holds result) ----
  float ss = cv.x * cv.x + cv.y * cv.y + cv.z * cv.z + cv.w * cv.w;
  #pragma unroll
  for (int off = 32; off > 0; off >>= 1) ss += __shfl_down(ss, off, 64);
  const float cn_inv_t = 1.0f / (fmaxf(sqrtf(ss), EPS) * TEMP);  // lane0-valid

  const float* nv_base = negs + (size_t)b * NNEG * D;
  unsigned long long mask = __ballot(nlab == label);

  float acc = 0.0f;
  while (mask) {
    // peel up to 8 set bits (wave-uniform); duplicates are cache-hit reloads
    int idx[8];
    int cnt = 1;
    idx[0] = __ffsll((long long)mask) - 1;
    mask &= mask - 1;
    #pragma unroll
    for (int t = 1; t < 8; ++t) {
      if (mask) {
        idx[t] = __ffsll((long long)mask) - 1;
        mask &= mask - 1;
        ++cnt;
      } else {
        idx[t] = idx[0];
      }
    }

    float dot[8], nn[8];
    #pragma unroll
    for (int t = 0; t < 8; ++t) {
      const float4 x =
          ((const float4*)(nv_base + (size_t)(neg_base + idx[t]) * D))[lane];
      dot[t] = cv.x * x.x + cv.y * x.y + cv.z * x.z + cv.w * x.w;
      nn[t]  = x.x * x.x + x.y * x.y + x.z * x.z + x.w * x.w;
    }
    #pragma unroll
    for (int off = 32; off > 0; off >>= 1) {
      #pragma unroll
      for (int t = 0; t < 8; ++t) {
        dot[t] += __shfl_down(dot[t], off, 64);
        nn[t]  += __shfl_down(nn[t],  off, 64);
      }
    }
    if (lane == 0) {
      #pragma unroll
      for (int t = 0; t < 8; ++t) {
        if (t < cnt) {
          const float sim = dot[t] * cn_inv_t / fmaxf(sqrtf(nn[t]), EPS);
          acc += expf(sim - SHIFT);
        }
      }
    }
  }

  // ---- pos_sim (one wave per batch) ----
  if (do_pos) {
    float pp = pv.x * pv.x + pv.y * pv.y + pv.z * pv.z + pv.w * pv.w;
    float cp = cv.x * pv.x + cv.y * pv.y + cv.z * pv.z + cv.w * pv.w;
    #pragma unroll
    for (int off = 32; off > 0; off >>= 1) {
      pp += __shfl_down(pp, off, 64);
      cp += __shfl_down(cp, off, 64);
    }
    if (lane == 0) {
      const float pos_sim = cp * cn_inv_t / fmaxf(sqrtf(pp), EPS);
      pos_sims[b] = pos_sim;
      acc += expf(pos_sim - SHIFT);
    }
  }

  // ---- per-block combine via tiny global scratch-free path: each wave
  // writes its own partial slot (no barriers, no LDS) ----
  if (lane == 0) partials[blk * 4 + wave] = acc;
}

// Kernel 2: one wave; lane b finalizes batch b, shuffle-tree global sum.
__global__ __launch_bounds__(64) void finalize_kernel(
    const float* __restrict__ partials,
    const float* __restrict__ pos_sims,
    float*       __restrict__ out) {
  const int lane = threadIdx.x;   // 0..63 == batch index
  float sum = 0.0f;
  #pragma unroll
  for (int t = 0; t < SLICES * 4; ++t) sum += partials[lane * SLICES * 4 + t];
  const float ps = pos_sims[lane];
  float loss = logf(sum) + SHIFT - ps;
  #pragma unroll
  for (int off = 32; off > 0; off >>= 1) loss += __shfl_down(loss, off, 64);
  if (lane == 0) out[0] = loss / (2.0f * B);
}

extern "C" void kernel_launch(void* const* d_in, const int* in_sizes, int n_in,
                              void* d_out, int out_size, void* d_ws, size_t ws_size,
                              hipStream_t stream) {
  const float* childrens      = (const float*)d_in[0];   // (B,J,D)
  const float* childrens_pos  = (const float*)d_in[1];   // (B,J,D)
  const float* childrens_negs = (const float*)d_in[2];   // (B,K,M,D)
  const int*   gt_labels      = (const int*)d_in[3];     // (B,J)
  const int*   gt_label_negs  = (const int*)d_in[4];     // (B,K,M)
  float* out = (float*)d_out;

  float* partials = (float*)d_ws;          // NBLK*4 floats (per-wave slots)
  float* pos_sims = partials + NBLK * 4;   // B floats

  neg_partial_kernel<<<NBLK, 256, 0, stream>>>(
      childrens, childrens_pos, gt_labels, childrens_negs, gt_label_negs,
      partials, pos_sims);
  finalize_kernel<<<1, 64, 0, stream>>>(partials, pos_sims, out);
}